// Round 13
// baseline (320.363 us; speedup 1.0000x reference)
//
#include <hip/hip_runtime.h>

#define NB 4
#define NC 256
#define NH 128
#define NW 256
#define ND 48
#define NHW (NH * NW)

__global__ __launch_bounds__(256, 2)
void corr_vol_kernel(const float* __restrict__ Lf,
                     const float* __restrict__ Rf,
                     float* __restrict__ out) {
  const int tid = threadIdx.x;
  const int b   = blockIdx.x >> 7;   // /128
  const int h   = blockIdx.x & 127;
  const int w0  = (tid & 63) << 2;   // 0..252
  const int i0  = (tid >> 6) * 12;   // 0,12,24,36

  const int rowbase = (b * NC * NH + h) * NW;

  // Per-lane static offsets (channel-0), clamped ONCE. Clamped lanes read
  // garbage that only feeds w<i outputs, which are zero-masked at store.
  const unsigned offL = (unsigned)(rowbase + w0);
  const int r0 = rowbase + w0 - i0 - 12;
  const unsigned off0 = (unsigned)(r0      > 0 ? r0      : 0);
  const unsigned off1 = (unsigned)(r0 + 4  > 0 ? r0 + 4  : 0);
  const unsigned off2 = (unsigned)(r0 + 8  > 0 ? r0 + 8  : 0);
  const unsigned off3 = (unsigned)(r0 + 12 > 0 ? r0 + 12 : 0);

  float acc[4][12];
  float l2[4] = {0.f, 0.f, 0.f, 0.f};
  float r2[16];
  #pragma unroll
  for (int q = 0; q < 16; ++q) r2[q] = 0.f;
  #pragma unroll
  for (int a = 0; a < 4; ++a)
    #pragma unroll
    for (int d = 0; d < 12; ++d) acc[a][d] = 0.f;

#define LOADCH(LV, R0, R1, R2, R3, ch)                                   \
  {                                                                      \
    const float* Lc = Lf + (size_t)(ch) * NHW;                           \
    const float* Rc = Rf + (size_t)(ch) * NHW;                           \
    LV = *reinterpret_cast<const float4*>(Lc + offL);                    \
    R0 = *reinterpret_cast<const float4*>(Rc + off0);                    \
    R1 = *reinterpret_cast<const float4*>(Rc + off1);                    \
    R2 = *reinterpret_cast<const float4*>(Rc + off2);                    \
    R3 = *reinterpret_cast<const float4*>(Rc + off3);                    \
  }

#define COMPUTECH(LV, R0, R1, R2, R3)                                    \
  {                                                                      \
    const float ll[4]  = {LV.x, LV.y, LV.z, LV.w};                       \
    const float rr[16] = {R0.x, R0.y, R0.z, R0.w,                        \
                          R1.x, R1.y, R1.z, R1.w,                        \
                          R2.x, R2.y, R2.z, R2.w,                        \
                          R3.x, R3.y, R3.z, R3.w};                       \
    _Pragma("unroll")                                                    \
    for (int a = 0; a < 4; ++a) l2[a] = fmaf(ll[a], ll[a], l2[a]);       \
    _Pragma("unroll")                                                    \
    for (int q = 1; q < 16; ++q) r2[q] = fmaf(rr[q], rr[q], r2[q]);      \
    _Pragma("unroll")                                                    \
    for (int dw = 0; dw < 4; ++dw)                                       \
      _Pragma("unroll")                                                  \
      for (int di = 0; di < 12; ++di)                                    \
        acc[dw][di] = fmaf(ll[dw], rr[dw - di + 12], acc[dw][di]);       \
  }

  // 2-buffer register pipeline: buffer refilled 2 channels ahead of use.
  float4 lA, rA0, rA1, rA2, rA3;
  float4 lB, rB0, rB1, rB2, rB3;
  LOADCH(lA, rA0, rA1, rA2, rA3, 0)
  LOADCH(lB, rB0, rB1, rB2, rB3, 1)

  #pragma unroll 1
  for (int cc = 0; cc < NC; cc += 2) {
    COMPUTECH(lA, rA0, rA1, rA2, rA3)
    {
      const int cn = (cc + 2 < NC) ? cc + 2 : NC - 1;  // uniform, branchless
      LOADCH(lA, rA0, rA1, rA2, rA3, cn)
    }
    COMPUTECH(lB, rB0, rB1, rB2, rB3)
    {
      const int cn = (cc + 3 < NC) ? cc + 3 : NC - 1;
      LOADCH(lB, rB0, rB1, rB2, rB3, cn)
    }
  }

  // per-thread normalization factors (F.normalize: x / max(||x||, eps))
  float invL[4];
  #pragma unroll
  for (int a = 0; a < 4; ++a)
    invL[a] = 1.0f / fmaxf(sqrtf(l2[a]), 1e-12f);
  float invR[16];
  invR[0] = 0.0f;
  #pragma unroll
  for (int q = 1; q < 16; ++q)
    invR[q] = 1.0f / fmaxf(sqrtf(r2[q]), 1e-12f);

  // scale + zero-mask (w < i -> exact 0) + coalesced float4 stores
  #pragma unroll
  for (int di = 0; di < 12; ++di) {
    const int i = i0 + di;
    float4 v;
    v.x = (w0 + 0 >= i) ? acc[0][di] * invL[0] * invR[0 - di + 12] : 0.0f;
    v.y = (w0 + 1 >= i) ? acc[1][di] * invL[1] * invR[1 - di + 12] : 0.0f;
    v.z = (w0 + 2 >= i) ? acc[2][di] * invL[2] * invR[2 - di + 12] : 0.0f;
    v.w = (w0 + 3 >= i) ? acc[3][di] * invL[3] * invR[3 - di + 12] : 0.0f;
    *reinterpret_cast<float4*>(out + ((size_t)(b * ND + i) * NH + h) * NW + w0) = v;
  }
#undef LOADCH
#undef COMPUTECH
}

extern "C" void kernel_launch(void* const* d_in, const int* in_sizes, int n_in,
                              void* d_out, int out_size, void* d_ws, size_t ws_size,
                              hipStream_t stream) {
  const float* Lf = (const float*)d_in[0];
  const float* Rf = (const float*)d_in[1];
  float* out = (float*)d_out;
  dim3 grid(NB * NH);
  dim3 block(256);
  corr_vol_kernel<<<grid, block, 0, stream>>>(Lf, Rf, out);
}